// Round 23
// baseline (52.262 us; speedup 1.0000x reference)
//
#include <hip/hip_runtime.h>

// Problem constants
#define NQ 20
#define DIMQ (1 << NQ)          // 2^20
#define NB 16                   // BATCH
#define NT 4                    // N_TERMS
#define RBITS 15                // low bits untouched by gates
#define NCOL (1 << (RBITS + 4)) // 2^15 r-values * 16 batches = 524288 columns

// U table layout in ws/LDS: per (k,b): 36 floats (16 complex interleaved + 4 pad)
//   base = (k*16 + b) * 36 ; entry (i,j): re at base + (i*4+j)*2, im at +1
#define USTRIDE 36
#define UTOT (64 * USTRIDE)     // 2304 floats = 9216 B

// Complex MAC via packed-FP32 VOP3P: o += u * s  (u=(ur,ui), s=(sr,si)).
__device__ __forceinline__ void cfma(float2& o, const float2 u, const float2 s) {
  asm("v_pk_fma_f32 %0, %1, %2, %0 op_sel_hi:[0,1,1]\n\t"
      "v_pk_fma_f32 %0, %1, %2, %0 op_sel:[1,1,0] op_sel_hi:[1,0,1] neg_lo:[1,0,0]"
      : "+v"(o) : "v"(u), "v"(s));
}
// o = u * s (no accumulate); early-clobber since %0 is written before last read.
__device__ __forceinline__ float2 cmul(const float2 u, const float2 s) {
  float2 o;
  asm("v_pk_mul_f32 %0, %1, %2 op_sel_hi:[0,1]\n\t"
      "v_pk_fma_f32 %0, %1, %2, %0 op_sel:[1,1,0] op_sel_hi:[1,0,1] neg_lo:[1,0,0]"
      : "=&v"(o) : "v"(u), "v"(s));
  return o;
}

// ---------------------------------------------------------------------------
// Kernel A: U[k,b] = exp(-i * H_k * t_{k,b}),  H_k = 0.5*(A + A^H), A = Hr + i Hi
// 256 threads: 64 tasks (k,b) x 4 rows. Scaling (2^-4) + 8-term Taylor +
// 4 squarings (trunc error ~1e-10, invisible at fp32 / 2.1e-4 threshold).
// ---------------------------------------------------------------------------
__global__ __launch_bounds__(256) void compute_u_kernel(
    const float* __restrict__ Hre, const float* __restrict__ Him,
    const float* __restrict__ tevo, float* __restrict__ uout) {
  __shared__ float er_s[64][4][4];
  __shared__ float ei_s[64][4][4];

  const int tid  = threadIdx.x;   // 0..255
  const int task = tid >> 2;      // 0..63
  const int row  = tid & 3;       // 0..3
  const int k    = task >> 4;     // 0..3
  const int b    = task & 15;     // 0..15

  float Ar[4][4], Ai[4][4];
#pragma unroll
  for (int i = 0; i < 4; i++) {
#pragma unroll
    for (int j = 0; j < 4; j++) {
      Ar[i][j] = Hre[k * 16 + i * 4 + j];
      Ai[i][j] = Him[k * 16 + i * 4 + j];
    }
  }
  const float t = tevo[k * NB + b];
  const float ts = t * (1.0f / 16.0f);  // scale 2^-4 folded in

  // G = -i * H * ts ; H = 0.5*(A + A^H)
  float Gr[4][4], Gi[4][4];
#pragma unroll
  for (int i = 0; i < 4; i++) {
#pragma unroll
    for (int j = 0; j < 4; j++) {
      const float hr = 0.5f * (Ar[i][j] + Ar[j][i]);
      const float hi = 0.5f * (Ai[i][j] - Ai[j][i]);
      Gr[i][j] = ts * hi;
      Gi[i][j] = -ts * hr;
    }
  }

  // Taylor: E = I + sum_{m=1..8} G^m/m!   (row `row` only; full G in regs)
  float Er[4], Ei[4], Tr[4], Ti[4];
#pragma unroll
  for (int j = 0; j < 4; j++) {
    Er[j] = (j == row) ? 1.0f : 0.0f;
    Ei[j] = 0.0f;
    Tr[j] = Er[j];
    Ti[j] = 0.0f;
  }
#pragma unroll
  for (int m = 1; m <= 8; m++) {
    const float inv = 1.0f / (float)m;
    float nr[4], ni[4];
#pragma unroll
    for (int j = 0; j < 4; j++) {
      float ar = 0.0f, ai = 0.0f;
#pragma unroll
      for (int p = 0; p < 4; p++) {
        ar += Tr[p] * Gr[p][j] - Ti[p] * Gi[p][j];
        ai += Tr[p] * Gi[p][j] + Ti[p] * Gr[p][j];
      }
      nr[j] = ar * inv;
      ni[j] = ai * inv;
    }
#pragma unroll
    for (int j = 0; j < 4; j++) {
      Tr[j] = nr[j]; Ti[j] = ni[j];
      Er[j] += nr[j]; Ei[j] += ni[j];
    }
  }

  // 4 squarings via LDS (uniform trip count -> barriers are safe)
  for (int q = 0; q < 4; q++) {
    __syncthreads();
#pragma unroll
    for (int j = 0; j < 4; j++) {
      er_s[task][row][j] = Er[j];
      ei_s[task][row][j] = Ei[j];
    }
    __syncthreads();
    float nr[4], ni[4];
#pragma unroll
    for (int j = 0; j < 4; j++) {
      float ar = 0.0f, ai = 0.0f;
#pragma unroll
      for (int p = 0; p < 4; p++) {
        ar += Er[p] * er_s[task][p][j] - Ei[p] * ei_s[task][p][j];
        ai += Er[p] * ei_s[task][p][j] + Ei[p] * er_s[task][p][j];
      }
      nr[j] = ar; ni[j] = ai;
    }
#pragma unroll
    for (int j = 0; j < 4; j++) { Er[j] = nr[j]; Ei[j] = ni[j]; }
  }

  // Store U rows: layout [k][b][16 complex interleaved], row stride 36 floats
  const int ubase = (k * 16 + b) * USTRIDE;
#pragma unroll
  for (int j = 0; j < 4; j++) {
    uout[ubase + (row * 4 + j) * 2]     = Er[j];
    uout[ubase + (row * 4 + j) * 2 + 1] = Ei[j];
  }
}

// ---------------------------------------------------------------------------
// Kernel B (r22 + two columns per thread, U reads amortized x2):
// Block = 128 columns; wave w owns g-quadrant w; lane l owns cols c0+l (A)
// and c0+l+64 (B). Cols l and l+64 share b = l&15, so every U row loaded
// from LDS feeds the cMACs of BOTH col-sets -> U DS reads per column-work
// halve (the dominant LDS-pipe term per r22 accounting).
// Tile layout [g][reA64|reB64|imA64|imB64] = [g][256 floats]; one DMA
// instr per g-plane (lanes 0-31 re cols 0..127 in 16B chunks? no --
// lanes 0-31: re cols 4l..4l+3; lanes 32-63: im cols 4(l-32)..+3), i.e.
// plane = re[128] | im[128] and col-set A = cols 0..63, B = 64..127 within
// each 128-float half. Paired (re,im) reads stay ds_read2 (delta 128 dw).
// Stores: per instr 64 lanes x 4B contiguous (A at c0, B at c0+64).
// LDS 32K tile + 9K U = 41.9KB -> 3 blocks/CU; bet: LDS-pipe cut (34->25us)
// beats the occupancy cap drop (50%->37.5%).
// ---------------------------------------------------------------------------
__global__ __launch_bounds__(256, 4) void apply_gates_kernel(
    const float* __restrict__ sre, const float* __restrict__ sim,
    const float* __restrict__ u, float* __restrict__ out) {
  __shared__ __align__(16) float ul[UTOT];       // 9216 B U table
  __shared__ __align__(16) float st[32 * 256];   // 32 KiB tile [g][re128|im128]
  const int tid = threadIdx.x;
  const int w   = tid >> 6;     // wave = owned quadrant (g bits [4:3])
  const int l   = tid & 63;     // lane = column within col-set
  const int c0  = blockIdx.x * 128;
  const int b   = l & 15;
  const int q0  = w & 1;        // g bit 3

  // (1) DMA: 8 instrs/wave, 1 KiB each = one full g-plane (re128|im128).
  //     lanes 0-31: re cols 4l..4l+3 ; lanes 32-63: im cols 4(l&31)..+3.
#pragma unroll
  for (int t = 0; t < 8; t++) {
    const int g = w * 8 + t;              // 0..31, wave-uniform
    const float* base = (l < 32) ? sre : sim;
    const float* src  = base + (g << 19) + c0 + (l & 31) * 4;
    float* dst = st + g * 256;            // wave-uniform base, lane*16B implicit
    __builtin_amdgcn_global_load_lds(
        (const __attribute__((address_space(1))) float*)(const void*)src,
        (__attribute__((address_space(3))) float*)(void*)dst, 16, 0, 0);
  }

  // (2) stage U table cooperatively (barrier below orders it)
#pragma unroll
  for (int q = 0; q < 9; q++) ul[tid + q * 256] = u[tid + q * 256];

  __syncthreads();   // drains DMA (vmcnt) + U writes (lgkmcnt)

  // (3) own quadrant, both col-sets: paired reads (ds_read2, delta 128 dw)
  float2 sA[8], sB[8];
#pragma unroll
  for (int m = 0; m < 8; m++) {
    const int a = (w * 8 + m) * 256 + l;
    sA[m].x = st[a];       sA[m].y = st[a + 128];
    sB[m].x = st[a + 64];  sB[m].y = st[a + 192];
  }

  float2 oA[8], oB[8];

  // ---- k = 3 (g bits [1:0]) : in-thread; initializes acc ----
  {
    const float* ub = &ul[(3 * 16 + b) * USTRIDE];
#pragma unroll
    for (int i = 0; i < 4; i++) {
      const float4 v0 = *(const float4*)(ub + i * 8);
      const float4 v1 = *(const float4*)(ub + i * 8 + 4);
      const float2 u0 = make_float2(v0.x, v0.y), u1 = make_float2(v0.z, v0.w);
      const float2 u2 = make_float2(v1.x, v1.y), u3 = make_float2(v1.z, v1.w);
#pragma unroll
      for (int h = 0; h < 2; h++) {
        const int om = h * 4 + i;
        oA[om] = cmul(u0, sA[h * 4 + 0]);
        cfma(oA[om], u1, sA[h * 4 + 1]);
        cfma(oA[om], u2, sA[h * 4 + 2]);
        cfma(oA[om], u3, sA[h * 4 + 3]);
        oB[om] = cmul(u0, sB[h * 4 + 0]);
        cfma(oB[om], u1, sB[h * 4 + 1]);
        cfma(oB[om], u2, sB[h * 4 + 2]);
        cfma(oB[om], u3, sB[h * 4 + 3]);
      }
    }
  }

  // ---- k = 2 (g bits [2:1]) : in-thread ----
  {
    const float* ub = &ul[(2 * 16 + b) * USTRIDE];
#pragma unroll
    for (int i = 0; i < 4; i++) {
      const float4 v0 = *(const float4*)(ub + i * 8);
      const float4 v1 = *(const float4*)(ub + i * 8 + 4);
      const float2 u0 = make_float2(v0.x, v0.y), u1 = make_float2(v0.z, v0.w);
      const float2 u2 = make_float2(v1.x, v1.y), u3 = make_float2(v1.z, v1.w);
#pragma unroll
      for (int l0 = 0; l0 < 2; l0++) {
        const int om = i * 2 + l0;
        cfma(oA[om], u0, sA[l0]);
        cfma(oA[om], u1, sA[2 + l0]);
        cfma(oA[om], u2, sA[4 + l0]);
        cfma(oA[om], u3, sA[6 + l0]);
        cfma(oB[om], u0, sB[l0]);
        cfma(oB[om], u1, sB[2 + l0]);
        cfma(oB[om], u2, sB[4 + l0]);
        cfma(oB[om], u3, sB[6 + l0]);
      }
    }
  }

  // ---- k = 1 (g bits [3:2]) + k = 0's j=w^1 term, per col-set (p scoped) ----
  {
    const float* ub1 = &ul[(1 * 16 + b) * USTRIDE];
    const float* ub0 = &ul[b * USTRIDE];
    const float2 u01 = *(const float2*)(ub0 + (w * 4 + (w ^ 1)) * 2);
    const int pq = w ^ 1;
#pragma unroll
    for (int cs = 0; cs < 2; cs++) {      // 0 = A, 1 = B
      float2* o = cs ? oB : oA;
      float2* s = cs ? sB : sA;
      const int co = cs * 64;
      float2 p[8];
#pragma unroll
      for (int m = 0; m < 8; m++) {
        const int a = (pq * 8 + m) * 256 + l + co;
        p[m].x = st[a];
        p[m].y = st[a + 128];
      }
#pragma unroll
      for (int mh = 0; mh < 2; mh++) {
        const int i = q0 * 2 + mh;
        const float* row = ub1 + i * 8;
#pragma unroll
        for (int j2 = 0; j2 < 2; j2++) {
          const float2 uo = *(const float2*)(row + (q0 * 2 + j2) * 2);
          const float2 up = *(const float2*)(row + ((q0 ^ 1) * 2 + j2) * 2);
#pragma unroll
          for (int ml = 0; ml < 4; ml++) {
            const int om = mh * 4 + ml;
            cfma(o[om], uo, s[j2 * 4 + ml]);
            cfma(o[om], up, p[j2 * 4 + ml]);
          }
        }
      }
      // k=0 term j = w^1 while p[] is live
#pragma unroll
      for (int m = 0; m < 8; m++) cfma(o[m], u01, p[m]);
    }
  }

  // ---- k = 0 remaining: j = w (own regs), j = w^2, w^3 (paired LDS) ----
  {
    const float* ub0 = &ul[b * USTRIDE];
    const float2 u00 = *(const float2*)(ub0 + (w * 4 + w) * 2);
#pragma unroll
    for (int m = 0; m < 8; m++) {
      cfma(oA[m], u00, sA[m]);
      cfma(oB[m], u00, sB[m]);
    }
#pragma unroll
    for (int d = 2; d < 4; d++) {
      const int jq = w ^ d;
      const float2 uj = *(const float2*)(ub0 + (w * 4 + jq) * 2);
#pragma unroll
      for (int m = 0; m < 8; m++) {
        const int a = (jq * 8 + m) * 256 + l;
        float2 tA, tB;
        tA.x = st[a];       tA.y = st[a + 128];
        tB.x = st[a + 64];  tB.y = st[a + 192];
        cfma(oA[m], uj, tA);
        cfma(oB[m], uj, tB);
      }
    }
  }

  // stores: 64 lanes x 4B contiguous = 256B (full lines) per instruction
#pragma unroll
  for (int m = 0; m < 8; m++) {
    const int offA = c0 + l + ((w * 8 + m) << 19);
    __builtin_nontemporal_store(oA[m].x, out + offA);               // real A
    __builtin_nontemporal_store(oA[m].y, out + offA + (1 << 24));   // imag A
    __builtin_nontemporal_store(oB[m].x, out + offA + 64);          // real B
    __builtin_nontemporal_store(oB[m].y, out + offA + 64 + (1 << 24)); // imag B
  }
}

extern "C" void kernel_launch(void* const* d_in, const int* in_sizes, int n_in,
                              void* d_out, int out_size, void* d_ws, size_t ws_size,
                              hipStream_t stream) {
  const float* Hre  = (const float*)d_in[0];
  const float* Him  = (const float*)d_in[1];
  const float* tevo = (const float*)d_in[2];
  const float* sre  = (const float*)d_in[3];
  const float* sim  = (const float*)d_in[4];
  float* out = (float*)d_out;
  float* uws = (float*)d_ws;  // UTOT floats = 9216 B

  compute_u_kernel<<<1, 256, 0, stream>>>(Hre, Him, tevo, uws);
  apply_gates_kernel<<<NCOL / 128, 256, 0, stream>>>(sre, sim, uws, out);
}

// Round 24
// 50.503 us; speedup vs baseline: 1.0348x; 1.0348x over previous
//
#include <hip/hip_runtime.h>

// Problem constants
#define NQ 20
#define DIMQ (1 << NQ)          // 2^20
#define NB 16                   // BATCH
#define NT 4                    // N_TERMS
#define RBITS 15                // low bits untouched by gates
#define NCOL (1 << (RBITS + 4)) // 2^15 r-values * 16 batches = 524288 columns

// U table layout in ws/LDS: per (k,b): 36 floats (16 complex interleaved + 4 pad)
//   base = (k*16 + b) * 36 ; entry (i,j): re at base + (i*4+j)*2, im at +1
#define USTRIDE 36
#define UTOT (64 * USTRIDE)     // 2304 floats = 9216 B

// Complex MAC via packed-FP32 VOP3P: o += u * s  (u=(ur,ui), s=(sr,si)).
__device__ __forceinline__ void cfma(float2& o, const float2 u, const float2 s) {
  asm("v_pk_fma_f32 %0, %1, %2, %0 op_sel_hi:[0,1,1]\n\t"
      "v_pk_fma_f32 %0, %1, %2, %0 op_sel:[1,1,0] op_sel_hi:[1,0,1] neg_lo:[1,0,0]"
      : "+v"(o) : "v"(u), "v"(s));
}
// o = u * s (no accumulate); early-clobber since %0 is written before last read.
__device__ __forceinline__ float2 cmul(const float2 u, const float2 s) {
  float2 o;
  asm("v_pk_mul_f32 %0, %1, %2 op_sel_hi:[0,1]\n\t"
      "v_pk_fma_f32 %0, %1, %2, %0 op_sel:[1,1,0] op_sel_hi:[1,0,1] neg_lo:[1,0,0]"
      : "=&v"(o) : "v"(u), "v"(s));
  return o;
}

// ---------------------------------------------------------------------------
// Kernel A: U[k,b] = exp(-i * H_k * t_{k,b}),  H_k = 0.5*(A + A^H), A = Hr + i Hi
// 256 threads: 64 tasks (k,b) x 4 rows. Scaling (2^-4) + 8-term Taylor +
// 4 squarings (trunc error ~1e-10, invisible at fp32 / 2.1e-4 threshold).
// ---------------------------------------------------------------------------
__global__ __launch_bounds__(256) void compute_u_kernel(
    const float* __restrict__ Hre, const float* __restrict__ Him,
    const float* __restrict__ tevo, float* __restrict__ uout) {
  __shared__ float er_s[64][4][4];
  __shared__ float ei_s[64][4][4];

  const int tid  = threadIdx.x;   // 0..255
  const int task = tid >> 2;      // 0..63
  const int row  = tid & 3;       // 0..3
  const int k    = task >> 4;     // 0..3
  const int b    = task & 15;     // 0..15

  float Ar[4][4], Ai[4][4];
#pragma unroll
  for (int i = 0; i < 4; i++) {
#pragma unroll
    for (int j = 0; j < 4; j++) {
      Ar[i][j] = Hre[k * 16 + i * 4 + j];
      Ai[i][j] = Him[k * 16 + i * 4 + j];
    }
  }
  const float t = tevo[k * NB + b];
  const float ts = t * (1.0f / 16.0f);  // scale 2^-4 folded in

  // G = -i * H * ts ; H = 0.5*(A + A^H)
  float Gr[4][4], Gi[4][4];
#pragma unroll
  for (int i = 0; i < 4; i++) {
#pragma unroll
    for (int j = 0; j < 4; j++) {
      const float hr = 0.5f * (Ar[i][j] + Ar[j][i]);
      const float hi = 0.5f * (Ai[i][j] - Ai[j][i]);
      Gr[i][j] = ts * hi;
      Gi[i][j] = -ts * hr;
    }
  }

  // Taylor: E = I + sum_{m=1..8} G^m/m!   (row `row` only; full G in regs)
  float Er[4], Ei[4], Tr[4], Ti[4];
#pragma unroll
  for (int j = 0; j < 4; j++) {
    Er[j] = (j == row) ? 1.0f : 0.0f;
    Ei[j] = 0.0f;
    Tr[j] = Er[j];
    Ti[j] = 0.0f;
  }
#pragma unroll
  for (int m = 1; m <= 8; m++) {
    const float inv = 1.0f / (float)m;
    float nr[4], ni[4];
#pragma unroll
    for (int j = 0; j < 4; j++) {
      float ar = 0.0f, ai = 0.0f;
#pragma unroll
      for (int p = 0; p < 4; p++) {
        ar += Tr[p] * Gr[p][j] - Ti[p] * Gi[p][j];
        ai += Tr[p] * Gi[p][j] + Ti[p] * Gr[p][j];
      }
      nr[j] = ar * inv;
      ni[j] = ai * inv;
    }
#pragma unroll
    for (int j = 0; j < 4; j++) {
      Tr[j] = nr[j]; Ti[j] = ni[j];
      Er[j] += nr[j]; Ei[j] += ni[j];
    }
  }

  // 4 squarings via LDS (uniform trip count -> barriers are safe)
  for (int q = 0; q < 4; q++) {
    __syncthreads();
#pragma unroll
    for (int j = 0; j < 4; j++) {
      er_s[task][row][j] = Er[j];
      ei_s[task][row][j] = Ei[j];
    }
    __syncthreads();
    float nr[4], ni[4];
#pragma unroll
    for (int j = 0; j < 4; j++) {
      float ar = 0.0f, ai = 0.0f;
#pragma unroll
      for (int p = 0; p < 4; p++) {
        ar += Er[p] * er_s[task][p][j] - Ei[p] * ei_s[task][p][j];
        ai += Er[p] * ei_s[task][p][j] + Ei[p] * er_s[task][p][j];
      }
      nr[j] = ar; ni[j] = ai;
    }
#pragma unroll
    for (int j = 0; j < 4; j++) { Er[j] = nr[j]; Ei[j] = ni[j]; }
  }

  // Store U rows: layout [k][b][16 complex interleaved], row stride 36 floats
  const int ubase = (k * 16 + b) * USTRIDE;
#pragma unroll
  for (int j = 0; j < 4; j++) {
    uout[ubase + (row * 4 + j) * 2]     = Er[j];
    uout[ubase + (row * 4 + j) * 2 + 1] = Ei[j];
  }
}

// ---------------------------------------------------------------------------
// Kernel B (r22 structure, the measured optimum at 50.2 us):
// Block = 64 columns; wave w owns g-quadrant w (g = w*8..w*8+7), lane l owns
// column c0+l. State tile layout: [g][re x64 | im x64] (128 floats/plane,
// 16 KiB total). DMA: 16 global_load_lds width-16 instrs; instr p covers
// planes 2p,2p+1 with PER-LANE source selection (lanes 0-15 re(2p),
// 16-31 im(2p), 32-47 re(2p+1), 48-63 im(2p+1)) -- the LDS dest is the
// required linear lane*16B, the global src is free per-lane (m104).
// Each (re,im) state read is a fused ds_read2_b32 (offset delta 64 dwords).
// Gates k=1..3 in-thread/quadrant-local; k=0 mixes quadrants via LDS reads.
// pk-FMA complex math; NT stores; 25.6 KB LDS -> 6 blocks/CU, ~50% occ.
// ---------------------------------------------------------------------------
__global__ __launch_bounds__(256, 4) void apply_gates_kernel(
    const float* __restrict__ sre, const float* __restrict__ sim,
    const float* __restrict__ u, float* __restrict__ out) {
  __shared__ __align__(16) float ul[UTOT];      // 9216 B U table
  __shared__ __align__(16) float st[32 * 128];  // 16 KiB tile [g][re64|im64]
  const int tid = threadIdx.x;
  const int w   = tid >> 6;     // wave = owned quadrant (g bits [4:3])
  const int l   = tid & 63;     // lane = column within block
  const int c0  = blockIdx.x * 64;
  const int b   = l & 15;
  const int q0  = w & 1;        // g bit 3

  // (1) DMA the state tile: 4 instrs/wave, 1 KiB each (2 planes/instr).
  //     instr p: sub = l>>4; g = 2p + (sub>>1); sub&1 ? im : re;
  //     cols (l&15)*4 .. +3 ; dest = st + p*256 floats (linear lane*16B).
#pragma unroll
  for (int t = 0; t < 4; t++) {
    const int p   = w * 4 + t;            // 0..15, wave-uniform
    const int sub = l >> 4;               // 0..3
    const int g   = 2 * p + (sub >> 1);   // 0..31
    const float* base = (sub & 1) ? sim : sre;
    const float* src  = base + (g << 19) + c0 + (l & 15) * 4;
    float* dst = st + p * 256;            // wave-uniform base, lane*16B implicit
    __builtin_amdgcn_global_load_lds(
        (const __attribute__((address_space(1))) float*)(const void*)src,
        (__attribute__((address_space(3))) float*)(void*)dst, 16, 0, 0);
  }

  // (2) stage U table cooperatively (barrier below orders it)
#pragma unroll
  for (int q = 0; q < 9; q++) ul[tid + q * 256] = u[tid + q * 256];

  __syncthreads();   // drains DMA (vmcnt) + U writes (lgkmcnt)

  // (3) own quadrant into registers: 8 paired reads (ds_read2_b32)
  float2 s[8];
#pragma unroll
  for (int m = 0; m < 8; m++) {
    const int a = (w * 8 + m) * 128 + l;
    s[m].x = st[a];
    s[m].y = st[a + 64];
  }

  float2 o[8];

  // ---- k = 3 (g bits [1:0]) : in-thread; initializes acc ----
  // o[h*4+i] = sum_j U3[i][j] * s[h*4+j]
  {
    const float* ub = &ul[(3 * 16 + b) * USTRIDE];
#pragma unroll
    for (int i = 0; i < 4; i++) {
      const float4 v0 = *(const float4*)(ub + i * 8);
      const float4 v1 = *(const float4*)(ub + i * 8 + 4);
      const float2 u0 = make_float2(v0.x, v0.y), u1 = make_float2(v0.z, v0.w);
      const float2 u2 = make_float2(v1.x, v1.y), u3 = make_float2(v1.z, v1.w);
#pragma unroll
      for (int h = 0; h < 2; h++) {
        const int om = h * 4 + i;
        o[om] = cmul(u0, s[h * 4 + 0]);
        cfma(o[om], u1, s[h * 4 + 1]);
        cfma(o[om], u2, s[h * 4 + 2]);
        cfma(o[om], u3, s[h * 4 + 3]);
      }
    }
  }

  // ---- k = 2 (g bits [2:1]) : in-thread ----
  // o[i*2+l0] += sum_j U2[i][j] * s[j*2+l0]
  {
    const float* ub = &ul[(2 * 16 + b) * USTRIDE];
#pragma unroll
    for (int i = 0; i < 4; i++) {
      const float4 v0 = *(const float4*)(ub + i * 8);
      const float4 v1 = *(const float4*)(ub + i * 8 + 4);
      const float2 u0 = make_float2(v0.x, v0.y), u1 = make_float2(v0.z, v0.w);
      const float2 u2 = make_float2(v1.x, v1.y), u3 = make_float2(v1.z, v1.w);
#pragma unroll
      for (int l0 = 0; l0 < 2; l0++) {
        const int om = i * 2 + l0;
        cfma(o[om], u0, s[l0]);
        cfma(o[om], u1, s[2 + l0]);
        cfma(o[om], u2, s[4 + l0]);
        cfma(o[om], u3, s[6 + l0]);
      }
    }
  }

  // ---- k = 1 (g bits [3:2]) + k = 0's j=w^1 term (reuses p[]) ----
  // out i = q0*2 + (m>>2); src bits[3:2]=(j3,j2): j3=q0 -> own s, j3=q0^1 ->
  // partner quadrant w^1 (p[], paired LDS reads).
  {
    float2 p[8];
    const int pq = w ^ 1;
#pragma unroll
    for (int m = 0; m < 8; m++) {
      const int a = (pq * 8 + m) * 128 + l;
      p[m].x = st[a];
      p[m].y = st[a + 64];
    }
    const float* ub1 = &ul[(1 * 16 + b) * USTRIDE];
#pragma unroll
    for (int mh = 0; mh < 2; mh++) {
      const int i = q0 * 2 + mh;
      const float* row = ub1 + i * 8;
#pragma unroll
      for (int j2 = 0; j2 < 2; j2++) {
        const float2 uo = *(const float2*)(row + (q0 * 2 + j2) * 2);
        const float2 up = *(const float2*)(row + ((q0 ^ 1) * 2 + j2) * 2);
#pragma unroll
        for (int ml = 0; ml < 4; ml++) {
          const int om = mh * 4 + ml;
          cfma(o[om], uo, s[j2 * 4 + ml]);
          cfma(o[om], up, p[j2 * 4 + ml]);
        }
      }
    }
    // k=0 term j = w^1 while p[] is live: o[m] += U0[w][w^1] * p[m]
    const float* ub0 = &ul[b * USTRIDE];
    const float2 u01 = *(const float2*)(ub0 + (w * 4 + (w ^ 1)) * 2);
#pragma unroll
    for (int m = 0; m < 8; m++) cfma(o[m], u01, p[m]);
  }

  // ---- k = 0 remaining: j = w (own regs), j = w^2, w^3 (paired LDS) ----
  {
    const float* ub0 = &ul[b * USTRIDE];
    const float2 u00 = *(const float2*)(ub0 + (w * 4 + w) * 2);
#pragma unroll
    for (int m = 0; m < 8; m++) cfma(o[m], u00, s[m]);
#pragma unroll
    for (int d = 2; d < 4; d++) {
      const int jq = w ^ d;
      const float2 uj = *(const float2*)(ub0 + (w * 4 + jq) * 2);
#pragma unroll
      for (int m = 0; m < 8; m++) {
        const int a = (jq * 8 + m) * 128 + l;
        float2 t;
        t.x = st[a];
        t.y = st[a + 64];
        cfma(o[m], uj, t);
      }
    }
  }

  // stores: 64 lanes x 4B contiguous = 256B (full lines) per instruction
#pragma unroll
  for (int m = 0; m < 8; m++) {
    const int off = c0 + l + ((w * 8 + m) << 19);
    __builtin_nontemporal_store(o[m].x, out + off);               // real
    __builtin_nontemporal_store(o[m].y, out + off + (1 << 24));   // imag
  }
}

extern "C" void kernel_launch(void* const* d_in, const int* in_sizes, int n_in,
                              void* d_out, int out_size, void* d_ws, size_t ws_size,
                              hipStream_t stream) {
  const float* Hre  = (const float*)d_in[0];
  const float* Him  = (const float*)d_in[1];
  const float* tevo = (const float*)d_in[2];
  const float* sre  = (const float*)d_in[3];
  const float* sim  = (const float*)d_in[4];
  float* out = (float*)d_out;
  float* uws = (float*)d_ws;  // UTOT floats = 9216 B

  compute_u_kernel<<<1, 256, 0, stream>>>(Hre, Him, tevo, uws);
  apply_gates_kernel<<<NCOL / 64, 256, 0, stream>>>(sre, sim, uws, out);
}